// Round 8
// baseline (218.877 us; speedup 1.0000x reference)
//
#include <hip/hip_runtime.h>

// Problem constants
#define NPIX   32768      // B*H*W
#define NEMB_  8192
#define EMB_   64
#define CH_    128
#define NCHUNK 8          // 8 chunks x 32 tiles x 32 codes
#define CAPP   512        // LDS pair-queue capacity (k_argfin)

// d_out layout (float elements)
#define OUT_OFF  0
#define ZQ_OFF   2097152
#define LOSS_OFF 4194304
#define IND_OFF  4194305

typedef _Float16 h8   __attribute__((ext_vector_type(8)));
typedef float    f16f __attribute__((ext_vector_type(16)));

// ---------------------------------------------------------------------------
// K1: codebook W-fragment pack + wsq + per-block max + init counters. grid 32.
__global__ __launch_bounds__(256) void k_wpack(
    const float* __restrict__ ew, float4* __restrict__ W4,
    float* __restrict__ wsq, float* __restrict__ wsqp,
    float* __restrict__ lacc, int* __restrict__ done)
{
    const int tid = threadIdx.x;
    const int m   = blockIdx.x * 256 + tid;
    const float4* wr = (const float4*)(ew + (size_t)m * EMB_);
    float w[EMB_];
    float s = 0.f;
    #pragma unroll
    for (int i = 0; i < 16; i++) {
        float4 v = wr[i];
        w[4*i] = v.x; w[4*i+1] = v.y; w[4*i+2] = v.z; w[4*i+3] = v.w;
        s += v.x*v.x + v.y*v.y + v.z*v.z + v.w*v.w;
    }
    wsq[m] = s;
    float sh = (float)(_Float16)s;
    float sl = s - sh;
    const int t  = m >> 5;
    const int li = m & 31;
    #pragma unroll
    for (int s5 = 0; s5 < 4; s5++) {
        #pragma unroll
        for (int h = 0; h < 2; h++) {
            h8 hh;
            #pragma unroll
            for (int j = 0; j < 8; j++) hh[j] = (_Float16)w[s5 * 16 + h * 8 + j];
            W4[(size_t)(t * 5 + s5) * 64 + h * 32 + li] = __builtin_bit_cast(float4, hh);
        }
    }
    {
        h8 hh;
        #pragma unroll
        for (int j = 0; j < 8; j++) hh[j] = (_Float16)0.f;
        hh[0] = (_Float16)sh; hh[1] = (_Float16)sl;
        W4[(size_t)(t * 5 + 4) * 64 + 0 * 32 + li] = __builtin_bit_cast(float4, hh);
        #pragma unroll
        for (int j = 0; j < 8; j++) hh[j] = (_Float16)0.f;
        W4[(size_t)(t * 5 + 4) * 64 + 1 * 32 + li] = __builtin_bit_cast(float4, hh);
    }
    __shared__ float red[256];
    red[tid] = s;
    __syncthreads();
    for (int o = 128; o > 0; o >>= 1) {
        if (tid < o) red[tid] = fmaxf(red[tid], red[tid + o]);
        __syncthreads();
    }
    if (tid == 0) wsqp[blockIdx.x] = red[0];
    if (blockIdx.x == 0 && tid == 0) { *lacc = 0.f; *done = 0; }
}

// ---------------------------------------------------------------------------
// K2: projection. grid 512, block 256 = 64 px x 4 e-quarters (eq wave-uniform).
__global__ __launch_bounds__(256) void k_proj(
    const float* __restrict__ z, const float* __restrict__ pw,
    const float* __restrict__ pb, float* __restrict__ z_e,
    float* __restrict__ xsq)
{
    __shared__ __align__(16) float wT[CH_ * EMB_];   // [c][e], 32 KB
    __shared__ float xp[4][64];
    const int tid = threadIdx.x;
    for (int i = tid; i < CH_ * EMB_; i += 256) {
        const int c = i >> 6, e = i & 63;
        wT[i] = pw[e * CH_ + c];
    }
    __syncthreads();

    const int px = tid & 63;
    const int eq = tid >> 6;                         // wave-uniform
    const int n  = blockIdx.x * 64 + px;
    const int b  = n >> 10;
    const int hw = n & 1023;
    const float* zp = z + (size_t)b * (CH_ * 1024) + hw;

    float acc[16];
    #pragma unroll
    for (int j = 0; j < 16; j++) acc[j] = 0.f;

    #pragma unroll 4
    for (int c = 0; c < CH_; c++) {
        const float zv = zp[(size_t)c * 1024];
        const float4* wr = (const float4*)(wT + c * EMB_ + eq * 16);
        float4 w0 = wr[0], w1 = wr[1], w2 = wr[2], w3 = wr[3];
        acc[0]  = fmaf(zv, w0.x, acc[0]);  acc[1]  = fmaf(zv, w0.y, acc[1]);
        acc[2]  = fmaf(zv, w0.z, acc[2]);  acc[3]  = fmaf(zv, w0.w, acc[3]);
        acc[4]  = fmaf(zv, w1.x, acc[4]);  acc[5]  = fmaf(zv, w1.y, acc[5]);
        acc[6]  = fmaf(zv, w1.z, acc[6]);  acc[7]  = fmaf(zv, w1.w, acc[7]);
        acc[8]  = fmaf(zv, w2.x, acc[8]);  acc[9]  = fmaf(zv, w2.y, acc[9]);
        acc[10] = fmaf(zv, w2.z, acc[10]); acc[11] = fmaf(zv, w2.w, acc[11]);
        acc[12] = fmaf(zv, w3.x, acc[12]); acc[13] = fmaf(zv, w3.y, acc[13]);
        acc[14] = fmaf(zv, w3.z, acc[14]); acc[15] = fmaf(zv, w3.w, acc[15]);
    }

    const float4* pb4 = (const float4*)(pb + eq * 16);
    float4 b0 = pb4[0], b1 = pb4[1], b2 = pb4[2], b3 = pb4[3];
    float bb[16] = {b0.x,b0.y,b0.z,b0.w, b1.x,b1.y,b1.z,b1.w,
                    b2.x,b2.y,b2.z,b2.w, b3.x,b3.y,b3.z,b3.w};
    float sq = 0.f;
    #pragma unroll
    for (int j = 0; j < 16; j++) { acc[j] += bb[j]; sq += acc[j] * acc[j]; }

    float4* zo = (float4*)(z_e + (size_t)n * EMB_ + eq * 16);
    zo[0] = make_float4(acc[0],  acc[1],  acc[2],  acc[3]);
    zo[1] = make_float4(acc[4],  acc[5],  acc[6],  acc[7]);
    zo[2] = make_float4(acc[8],  acc[9],  acc[10], acc[11]);
    zo[3] = make_float4(acc[12], acc[13], acc[14], acc[15]);
    xp[eq][px] = sq;
    __syncthreads();
    if (tid < 64)
        xsq[blockIdx.x * 64 + tid] = xp[0][tid] + xp[1][tid] + xp[2][tid] + xp[3][tid];
}

// ---------------------------------------------------------------------------
// K3: coarse MFMA pass with 2-deep A prefetch. grid 512, wave = 128 px x 1 chunk.
__global__ __launch_bounds__(256, 2) void k_pass1(
    const float4* __restrict__ W4, const float* __restrict__ z_e,
    float* __restrict__ s1a, float* __restrict__ s2a, float* __restrict__ s3a,
    int* __restrict__ i1a, int* __restrict__ i2a)
{
    const int lane  = threadIdx.x & 63;
    const int wv    = threadIdx.x >> 6;
    const int pxg   = blockIdx.x >> 1;
    const int chunk = (blockIdx.x & 1) * 4 + wv;
    const int n0    = pxg * 128;
    const int hlf   = lane >> 5;

    // B-fragments (128 px per wave, lane-half = e-half)
    h8 bfr[4][5];
    #pragma unroll
    for (int j = 0; j < 4; j++) {
        const int px = n0 + j * 32 + (lane & 31);
        const float* zr = z_e + (size_t)px * EMB_ + (hlf << 3);
        #pragma unroll
        for (int s5 = 0; s5 < 4; s5++) {
            float4 u0 = *(const float4*)(zr + s5 * 16);
            float4 u1 = *(const float4*)(zr + s5 * 16 + 4);
            h8 hh;
            hh[0]=(_Float16)u0.x; hh[1]=(_Float16)u0.y; hh[2]=(_Float16)u0.z; hh[3]=(_Float16)u0.w;
            hh[4]=(_Float16)u1.x; hh[5]=(_Float16)u1.y; hh[6]=(_Float16)u1.z; hh[7]=(_Float16)u1.w;
            bfr[j][s5] = hh;
        }
        h8 hh;
        #pragma unroll
        for (int q = 0; q < 8; q++) hh[q] = (_Float16)0.f;
        if (hlf == 0) { hh[0] = (_Float16)-0.5f; hh[1] = (_Float16)-0.5f; }
        bfr[j][4] = hh;
    }

    const f16f kzero = {0,0,0,0,0,0,0,0,0,0,0,0,0,0,0,0};
    float s1[4], s2[4], s3[4];
    int   i1[4], i2[4];
    #pragma unroll
    for (int j = 0; j < 4; j++) { s1[j]=s2[j]=s3[j]=-3.0e38f; i1[j]=i2[j]=0; }

    const int tb = chunk * 32;
    const float4* Wb = W4 + (size_t)tb * 320 + lane;
    float4 A0[5], A1[5];
    #pragma unroll
    for (int s = 0; s < 5; s++) A0[s] = Wb[s * 64];
    #pragma unroll
    for (int s = 0; s < 5; s++) A1[s] = Wb[320 + s * 64];

#define TILE_BODY(AB, TT, PF)                                                  \
    {                                                                          \
        const int gt = tb + (TT);                                              \
        f16f acc[4];                                                           \
        _Pragma("unroll")                                                      \
        for (int j = 0; j < 4; j++)                                            \
            acc[j] = __builtin_amdgcn_mfma_f32_32x32x16_f16(                   \
                __builtin_bit_cast(h8, AB[0]), bfr[j][0], kzero, 0, 0, 0);     \
        _Pragma("unroll")                                                      \
        for (int s = 1; s < 5; s++) {                                          \
            h8 a = __builtin_bit_cast(h8, AB[s]);                              \
            _Pragma("unroll")                                                  \
            for (int j = 0; j < 4; j++)                                        \
                acc[j] = __builtin_amdgcn_mfma_f32_32x32x16_f16(a, bfr[j][s],  \
                                                                acc[j],0,0,0); \
        }                                                                      \
        {   /* prefetch 2 ahead (clamped) */                                   \
            const int tp = (PF) < 32 ? (PF) : 31;                              \
            const float4* wp = Wb + (size_t)tp * 320;                          \
            _Pragma("unroll")                                                  \
            for (int s = 0; s < 5; s++) AB[s] = wp[s * 64];                    \
        }                                                                      \
        _Pragma("unroll")                                                      \
        for (int j = 0; j < 4; j++) {                                          \
            float t0 = fmaxf(fmaxf(acc[j][0],  acc[j][1]),  acc[j][2]);        \
            float t1 = fmaxf(fmaxf(acc[j][3],  acc[j][4]),  acc[j][5]);        \
            float t2 = fmaxf(fmaxf(acc[j][6],  acc[j][7]),  acc[j][8]);        \
            float t3 = fmaxf(fmaxf(acc[j][9],  acc[j][10]), acc[j][11]);       \
            float t4 = fmaxf(fmaxf(acc[j][12], acc[j][13]), acc[j][14]);       \
            float v  = fmaxf(fmaxf(fmaxf(t0, t1), fmaxf(t2, t3)),              \
                             fmaxf(t4, acc[j][15]));                           \
            v = fmaxf(v, __shfl_xor(v, 32));                                   \
            bool c1 = v > s1[j];                                               \
            bool c2 = v > s2[j];                                               \
            int  cand = c1 ? i1[j] : gt;                                       \
            i2[j] = c2 ? cand : i2[j];                                         \
            s3[j] = fmaxf(fminf(s2[j], v), s3[j]);                             \
            s3[j] = fminf(s3[j], fmaxf(s2[j], v));                             \
            s2[j] = fmaxf(fminf(s1[j], v), fminf(s2[j], fmaxf(s1[j], v)));     \
            i1[j] = c1 ? gt : i1[j];                                           \
            s1[j] = fmaxf(s1[j], v);                                           \
        }                                                                      \
    }

    for (int tt = 0; tt < 32; tt += 2) {
        TILE_BODY(A0, tt,     tt + 2)
        TILE_BODY(A1, tt + 1, tt + 3)
    }
#undef TILE_BODY

    if (lane < 32) {
        #pragma unroll
        for (int j = 0; j < 4; j++) {
            const size_t o = (size_t)chunk * NPIX + n0 + j * 32 + lane;
            s1a[o] = s1[j]; s2a[o] = s2[j]; s3a[o] = s3[j];
            i1a[o] = i1[j]; i2a[o] = i2[j];
        }
    }
}

// ---------------------------------------------------------------------------
// ordered-float key: lexicographic (dist, index) min == np argmin semantics
__device__ __forceinline__ unsigned long long pack_key(float d, int m)
{
    unsigned fb = __float_as_uint(d);
    fb ^= ((int)fb < 0) ? 0xFFFFFFFFu : 0x80000000u;
    return ((unsigned long long)fb << 32) | (unsigned)m;
}

// full-row exact distance key (fallback path)
__device__ __forceinline__ unsigned long long lane_key_full(
    int m, const float* __restrict__ xr,
    const float* __restrict__ ew, const float* __restrict__ wsq)
{
    const float4* w4 = (const float4*)(ew + (size_t)m * EMB_);
    const float4* x4 = (const float4*)xr;
    float a0 = 0.f, a1 = 0.f;
    #pragma unroll
    for (int i = 0; i < 8; i++) {
        float4 wv = w4[2*i],   xv = x4[2*i];
        float4 wu = w4[2*i+1], xu = x4[2*i+1];
        a0 = fmaf(wv.x, xv.x, a0); a0 = fmaf(wv.y, xv.y, a0);
        a0 = fmaf(wv.z, xv.z, a0); a0 = fmaf(wv.w, xv.w, a0);
        a1 = fmaf(wu.x, xu.x, a1); a1 = fmaf(wu.y, xu.y, a1);
        a1 = fmaf(wu.z, xu.z, a1); a1 = fmaf(wu.w, xu.w, a1);
    }
    float d = fmaf(-2.f, a0 + a1, wsq[m]);
    return pack_key(d, m);
}

// ---------------------------------------------------------------------------
// K4: select + finalize, 32 px/block, grid 1024 (high occupancy).
__global__ __launch_bounds__(256) void k_argfin(
    const float* __restrict__ s1a, const float* __restrict__ s2a,
    const float* __restrict__ s3a, const int* __restrict__ i1a,
    const int* __restrict__ i2a, const float* __restrict__ xsq,
    const float* __restrict__ wsqp, const float* __restrict__ wsq,
    const float* __restrict__ ew, const float* __restrict__ z_e,
    float* __restrict__ out, float* __restrict__ lacc, int* __restrict__ done)
{
    __shared__ __align__(16) float xs[32][68];       // z_e rows, later winners
    __shared__ float s1s[256];                       // [px][ch]
    __shared__ float thr_s[32];
    __shared__ int   pairs[CAPP];
    __shared__ unsigned long long wbest[4][32];      // wave-private
    __shared__ int   winner_s[32];
    __shared__ int   smask[32];
    __shared__ float lred[256];
    __shared__ int   npair_s;
    __shared__ float wm_s;

    const int tid  = threadIdx.x;
    const int wv   = tid >> 6;
    const int lane = tid & 63;
    const int n0   = blockIdx.x * 32;

    if (tid == 0) npair_s = 0;
    if (tid < 32) smask[tid] = 0;
    if (tid < 128) wbest[tid >> 5][tid & 31] = ~0ULL;
    if (tid < 32) {
        float w = wsqp[tid];
        #pragma unroll
        for (int o = 16; o > 0; o >>= 1) w = fmaxf(w, __shfl_xor(w, o));
        if (tid == 0) wm_s = w;
    }
    // stage x (32 px x 64 floats), coalesced, 2 float4 per thread
    #pragma unroll
    for (int k = 0; k < 2; k++) {
        const int idx = k * 256 + tid;
        const int px = idx >> 4, i = idx & 15;
        float4 v = *(const float4*)(z_e + (size_t)(n0 + px) * EMB_ + i * 4);
        ((float4*)&xs[px][0])[i] = v;
    }
    // stats: 256 cells (8 ch x 32 px), 1 per thread, coalesced in px
    const int ch = tid >> 5, pxc = tid & 31;
    const size_t so = (size_t)ch * NPIX + n0 + pxc;
    const float cs1 = s1a[so], cs2 = s2a[so], cs3 = s3a[so];
    const int   ci1 = i1a[so], ci2 = i2a[so];
    s1s[pxc * 8 + ch] = cs1;
    __syncthreads();
    if (tid < 32) {
        float s1g = s1s[tid * 8];
        #pragma unroll
        for (int c = 1; c < 8; c++) s1g = fmaxf(s1g, s1s[tid * 8 + c]);
        float E = 0.00125f * sqrtf(xsq[n0 + tid] * wm_s) + 1e-5f * wm_s + 3e-4f;
        thr_s[tid] = s1g - 2.0f * E;
    }
    __syncthreads();
    // push candidate (px, tile) pairs
    {
        const float th = thr_s[pxc];
        if (cs3 >= th) {
            int pos = atomicAdd(&npair_s, 32);
            if (pos + 32 <= CAPP) {
                for (int t = 0; t < 32; t++) pairs[pos + t] = (pxc << 8) | (ch * 32 + t);
            } else {
                for (int t = 0; t < 32; t++)
                    if (pos + t < CAPP) pairs[pos + t] = -1;
                smask[pxc] = 1;
            }
        } else {
            if (cs1 >= th) {
                int pos = atomicAdd(&npair_s, 1);
                if (pos < CAPP) pairs[pos] = (pxc << 8) | ci1; else smask[pxc] = 1;
            }
            if (cs2 >= th) {
                int pos = atomicAdd(&npair_s, 1);
                if (pos < CAPP) pairs[pos] = (pxc << 8) | ci2; else smask[pxc] = 1;
            }
        }
    }
    __syncthreads();
    const int np = min(npair_s, CAPP);

    // drain: 1 pair per wave-iteration; 2 lanes per code (half-row dots)
    const int hlf = lane >> 5;
    for (int i = wv; i < np; i += 4) {
        const int pr = pairs[i];
        if (pr < 0) continue;
        const int p = pr >> 8;
        if (smask[p]) continue;
        const int m = (pr & 255) * 32 + (lane & 31);
        const float4* w4 = (const float4*)(ew + (size_t)m * EMB_ + (hlf << 5));
        const float4* x4 = (const float4*)(&xs[p][hlf << 5]);
        float dp = 0.f;
        #pragma unroll
        for (int q = 0; q < 8; q++) {
            float4 wvv = w4[q], xv = x4[q];
            dp = fmaf(wvv.x, xv.x, dp); dp = fmaf(wvv.y, xv.y, dp);
            dp = fmaf(wvv.z, xv.z, dp); dp = fmaf(wvv.w, xv.w, dp);
        }
        dp += __shfl_xor(dp, 32);                    // full 64-dim dot
        unsigned long long key = pack_key(fmaf(-2.f, dp, wsq[m]), m);
        #pragma unroll
        for (int o = 1; o < 32; o <<= 1) {
            unsigned long long ok = __shfl_xor(key, o);
            key = ok < key ? ok : key;
        }
        if (lane == 0) {
            unsigned long long cur = wbest[wv][p];   // wave-private: no atomic
            wbest[wv][p] = key < cur ? key : cur;
        }
    }
    // overflow fallback: full codebook rescan (statistically never)
    for (int p = wv; p < 32; p += 4) {
        if (!smask[p]) continue;
        unsigned long long bk = ~0ULL;
        for (int it = 0; it < 128; it++) {
            const int m = it * 64 + lane;
            unsigned long long k2 = lane_key_full(m, &xs[p][0], ew, wsq);
            bk = k2 < bk ? k2 : bk;
        }
        #pragma unroll
        for (int o = 1; o < 64; o <<= 1) {
            unsigned long long ok = __shfl_xor(bk, o);
            bk = ok < bk ? ok : bk;
        }
        if (lane == 0) {
            unsigned long long cur = wbest[wv][p];
            wbest[wv][p] = bk < cur ? bk : cur;
        }
    }
    __syncthreads();
    if (tid < 32) {
        unsigned long long k0 = wbest[0][tid];
        unsigned long long k1 = wbest[1][tid];
        unsigned long long k2 = wbest[2][tid];
        unsigned long long k3 = wbest[3][tid];
        k0 = k1 < k0 ? k1 : k0;
        k2 = k3 < k2 ? k3 : k2;
        k0 = k2 < k0 ? k2 : k0;
        const int win = (int)(unsigned)(k0 & 0xFFFFFFFFULL);
        winner_s[tid] = win;
        out[IND_OFF + n0 + tid] = (float)win;
    }
    __syncthreads();
    // gather winner rows (8 threads/px), z_q writes, loss partials
    float lsum = 0.f;
    {
        const int px = tid >> 3, sg = tid & 7;
        const int win = winner_s[px];
        const float4* wr = (const float4*)(ew + (size_t)win * EMB_ + sg * 8);
        float4* xr  = (float4*)(&xs[px][sg * 8]);
        float4* zq4 = (float4*)(out + ZQ_OFF + (size_t)(n0 + px) * EMB_ + sg * 8);
        #pragma unroll
        for (int i = 0; i < 2; i++) {
            float4 w4v = wr[i];
            float4 z4  = xr[i];
            float d0 = w4v.x - z4.x, d1 = w4v.y - z4.y;
            float d2 = w4v.z - z4.z, d3 = w4v.w - z4.w;
            lsum += d0*d0 + d1*d1 + d2*d2 + d3*d3;
            xr[i]  = w4v;
            zq4[i] = w4v;
        }
    }
    __syncthreads();
    // transposed out writes: 2048 floats, px fastest (128-B segments)
    {
        const int bI  = n0 >> 10;
        const int hw0 = n0 & 1023;
        float* ob = out + OUT_OFF + (size_t)bI * (EMB_ * 1024) + hw0;
        #pragma unroll
        for (int r = 0; r < 8; r++) {
            const int idx = r * 256 + tid;
            const int e = idx >> 5, px = idx & 31;
            ob[(size_t)e * 1024 + px] = xs[px][e];
        }
    }
    // loss reduction + final scalar (last of 1024 blocks)
    lred[tid] = lsum;
    __syncthreads();
    for (int o = 128; o > 0; o >>= 1) {
        if (tid < o) lred[tid] += lred[tid + o];
        __syncthreads();
    }
    if (tid == 0) {
        atomicAdd(lacc, lred[0]);
        __threadfence();
        int old = atomicAdd(done, 1);
        if (old == (int)gridDim.x - 1) {
            float tot = atomicAdd(lacc, 0.0f);
            out[LOSS_OFF] = 12.5f * (tot / 2097152.0f);
        }
    }
}

// ---------------------------------------------------------------------------
extern "C" void kernel_launch(void* const* d_in, const int* in_sizes, int n_in,
                              void* d_out, int out_size, void* d_ws, size_t ws_size,
                              hipStream_t stream)
{
    const float* z  = (const float*)d_in[0];
    const float* pw = (const float*)d_in[1];
    const float* pb = (const float*)d_in[2];
    const float* ew = (const float*)d_in[3];
    float* out = (float*)d_out;

    char* ws = (char*)d_ws;
    float4* W4   = (float4*)(ws);                      // 1,310,720
    float*  s1a  = (float*) (ws + 1310720);            // 1,048,576
    float*  s2a  = (float*) (ws + 2359296);            // 1,048,576
    float*  s3a  = (float*) (ws + 3407872);            // 1,048,576
    int*    i1a  = (int*)   (ws + 4456448);            // 1,048,576
    int*    i2a  = (int*)   (ws + 5505024);            // 1,048,576
    float*  xsq  = (float*) (ws + 6553600);            //   131,072
    float*  wsq  = (float*) (ws + 6684672);            //    32,768
    float*  wsqp = (float*) (ws + 6717440);            //       128
    float*  lacc = (float*) (ws + 6717568);            //         4
    int*    done = (int*)   (ws + 6717572);            //         4

    float* z_e = out + ZQ_OFF;   // z_q_flat region doubles as z_e scratch

    hipLaunchKernelGGL(k_wpack,  dim3(32),   dim3(256), 0, stream,
                       ew, W4, wsq, wsqp, lacc, done);
    hipLaunchKernelGGL(k_proj,   dim3(512),  dim3(256), 0, stream,
                       z, pw, pb, z_e, xsq);
    hipLaunchKernelGGL(k_pass1,  dim3(512),  dim3(256), 0, stream,
                       W4, z_e, s1a, s2a, s3a, i1a, i2a);
    hipLaunchKernelGGL(k_argfin, dim3(1024), dim3(256), 0, stream,
                       s1a, s2a, s3a, i1a, i2a, xsq, wsqp, wsq, ew, z_e,
                       out, lacc, done);
}

// Round 9
// 186.642 us; speedup vs baseline: 1.1727x; 1.1727x over previous
//
#include <hip/hip_runtime.h>

// Problem constants
#define NPIX   32768      // B*H*W
#define NEMB_  8192
#define EMB_   64
#define CH_    128
#define CAPP   512        // LDS pair-queue capacity

// d_out layout (float elements)
#define OUT_OFF  0
#define ZQ_OFF   2097152
#define LOSS_OFF 4194304
#define IND_OFF  4194305

typedef _Float16 h8   __attribute__((ext_vector_type(8)));
typedef float    f16f __attribute__((ext_vector_type(16)));

// ---------------------------------------------------------------------------
// K1: codebook W-fragment pack + wsq + per-block max + init counters. grid 32.
__global__ __launch_bounds__(256) void k_wpack(
    const float* __restrict__ ew, float4* __restrict__ W4,
    float* __restrict__ wsq, float* __restrict__ wsqp,
    float* __restrict__ lacc, int* __restrict__ done)
{
    const int tid = threadIdx.x;
    const int m   = blockIdx.x * 256 + tid;
    const float4* wr = (const float4*)(ew + (size_t)m * EMB_);
    float w[EMB_];
    float s = 0.f;
    #pragma unroll
    for (int i = 0; i < 16; i++) {
        float4 v = wr[i];
        w[4*i] = v.x; w[4*i+1] = v.y; w[4*i+2] = v.z; w[4*i+3] = v.w;
        s += v.x*v.x + v.y*v.y + v.z*v.z + v.w*v.w;
    }
    wsq[m] = s;
    float sh = (float)(_Float16)s;
    float sl = s - sh;
    const int t  = m >> 5;
    const int li = m & 31;
    #pragma unroll
    for (int s5 = 0; s5 < 4; s5++) {
        #pragma unroll
        for (int h = 0; h < 2; h++) {
            h8 hh;
            #pragma unroll
            for (int j = 0; j < 8; j++) hh[j] = (_Float16)w[s5 * 16 + h * 8 + j];
            W4[(size_t)(t * 5 + s5) * 64 + h * 32 + li] = __builtin_bit_cast(float4, hh);
        }
    }
    {
        h8 hh;
        #pragma unroll
        for (int j = 0; j < 8; j++) hh[j] = (_Float16)0.f;
        hh[0] = (_Float16)sh; hh[1] = (_Float16)sl;
        W4[(size_t)(t * 5 + 4) * 64 + 0 * 32 + li] = __builtin_bit_cast(float4, hh);
        #pragma unroll
        for (int j = 0; j < 8; j++) hh[j] = (_Float16)0.f;
        W4[(size_t)(t * 5 + 4) * 64 + 1 * 32 + li] = __builtin_bit_cast(float4, hh);
    }
    __shared__ float red[256];
    red[tid] = s;
    __syncthreads();
    for (int o = 128; o > 0; o >>= 1) {
        if (tid < o) red[tid] = fmaxf(red[tid], red[tid + o]);
        __syncthreads();
    }
    if (tid == 0) wsqp[blockIdx.x] = red[0];
    if (blockIdx.x == 0 && tid == 0) { *lacc = 0.f; *done = 0; }
}

// ---------------------------------------------------------------------------
// K2: projection. grid 512, block 256 = 64 px x 4 e-quarters (eq wave-uniform).
__global__ __launch_bounds__(256) void k_proj(
    const float* __restrict__ z, const float* __restrict__ pw,
    const float* __restrict__ pb, float* __restrict__ z_e,
    float* __restrict__ xsq)
{
    __shared__ __align__(16) float wT[CH_ * EMB_];   // [c][e], 32 KB
    __shared__ float xp[4][64];
    const int tid = threadIdx.x;
    for (int i = tid; i < CH_ * EMB_; i += 256) {
        const int c = i >> 6, e = i & 63;
        wT[i] = pw[e * CH_ + c];
    }
    __syncthreads();

    const int px = tid & 63;
    const int eq = tid >> 6;                         // wave-uniform
    const int n  = blockIdx.x * 64 + px;
    const int b  = n >> 10;
    const int hw = n & 1023;
    const float* zp = z + (size_t)b * (CH_ * 1024) + hw;

    float acc[16];
    #pragma unroll
    for (int j = 0; j < 16; j++) acc[j] = 0.f;

    #pragma unroll 4
    for (int c = 0; c < CH_; c++) {
        const float zv = zp[(size_t)c * 1024];
        const float4* wr = (const float4*)(wT + c * EMB_ + eq * 16);
        float4 w0 = wr[0], w1 = wr[1], w2 = wr[2], w3 = wr[3];
        acc[0]  = fmaf(zv, w0.x, acc[0]);  acc[1]  = fmaf(zv, w0.y, acc[1]);
        acc[2]  = fmaf(zv, w0.z, acc[2]);  acc[3]  = fmaf(zv, w0.w, acc[3]);
        acc[4]  = fmaf(zv, w1.x, acc[4]);  acc[5]  = fmaf(zv, w1.y, acc[5]);
        acc[6]  = fmaf(zv, w1.z, acc[6]);  acc[7]  = fmaf(zv, w1.w, acc[7]);
        acc[8]  = fmaf(zv, w2.x, acc[8]);  acc[9]  = fmaf(zv, w2.y, acc[9]);
        acc[10] = fmaf(zv, w2.z, acc[10]); acc[11] = fmaf(zv, w2.w, acc[11]);
        acc[12] = fmaf(zv, w3.x, acc[12]); acc[13] = fmaf(zv, w3.y, acc[13]);
        acc[14] = fmaf(zv, w3.z, acc[14]); acc[15] = fmaf(zv, w3.w, acc[15]);
    }

    const float4* pb4 = (const float4*)(pb + eq * 16);
    float4 b0 = pb4[0], b1 = pb4[1], b2 = pb4[2], b3 = pb4[3];
    float bb[16] = {b0.x,b0.y,b0.z,b0.w, b1.x,b1.y,b1.z,b1.w,
                    b2.x,b2.y,b2.z,b2.w, b3.x,b3.y,b3.z,b3.w};
    float sq = 0.f;
    #pragma unroll
    for (int j = 0; j < 16; j++) { acc[j] += bb[j]; sq += acc[j] * acc[j]; }

    float4* zo = (float4*)(z_e + (size_t)n * EMB_ + eq * 16);
    zo[0] = make_float4(acc[0],  acc[1],  acc[2],  acc[3]);
    zo[1] = make_float4(acc[4],  acc[5],  acc[6],  acc[7]);
    zo[2] = make_float4(acc[8],  acc[9],  acc[10], acc[11]);
    zo[3] = make_float4(acc[12], acc[13], acc[14], acc[15]);
    xp[eq][px] = sq;
    __syncthreads();
    if (tid < 64)
        xsq[blockIdx.x * 64 + tid] = xp[0][tid] + xp[1][tid] + xp[2][tid] + xp[3][tid];
}

// ---------------------------------------------------------------------------
// ordered-float key: lexicographic (dist, index) min == np argmin semantics
__device__ __forceinline__ unsigned long long pack_key(float d, int m)
{
    unsigned fb = __float_as_uint(d);
    fb ^= ((int)fb < 0) ? 0xFFFFFFFFu : 0x80000000u;
    return ((unsigned long long)fb << 32) | (unsigned)m;
}

// ---------------------------------------------------------------------------
// K3 fused: MFMA coarse scan (wave = 64px x 2 chunks) with LDS stats ->
// certify -> COALESCED tile drain -> finalize + loss. grid 512, 2 blocks/CU.
__global__ __launch_bounds__(256, 2) void k_fused2(
    const float4* __restrict__ W4, const float* __restrict__ z_e,
    const float* __restrict__ xsq, const float* __restrict__ wsqp,
    const float* __restrict__ wsq, const float* __restrict__ ew,
    float* __restrict__ out, float* __restrict__ lacc, int* __restrict__ done)
{
    __shared__ __align__(16) float xs[64][68];       // z_e rows, later winners
    __shared__ float s1s[512], s2s[512], s3s[512];   // [px][ch]
    __shared__ short i1s[512], i2s[512];
    __shared__ float thr_s[64];
    __shared__ int   pairs[CAPP];
    __shared__ unsigned long long wbest[4][64];      // wave-private
    __shared__ int   winner_s[64];
    __shared__ int   smask[64];
    __shared__ float lred[256];
    __shared__ int   npair_s;
    __shared__ float wm_s;

    const int tid  = threadIdx.x;
    const int wv   = tid >> 6;
    const int lane = tid & 63;
    const int n0   = blockIdx.x * 64;
    const int hlf  = lane >> 5;

    if (tid == 0) npair_s = 0;
    if (tid < 64) smask[tid] = 0;
    wbest[wv][lane] = ~0ULL;
    if (tid < 32) {
        float w = wsqp[tid];
        #pragma unroll
        for (int o = 16; o > 0; o >>= 1) w = fmaxf(w, __shfl_xor(w, o));
        if (tid == 0) wm_s = w;
    }
    // ---- stage xs coalesced (64 px x 64 f) ----
    #pragma unroll
    for (int k = 0; k < 4; k++) {
        const int idx = k * 256 + tid;
        const int px = idx >> 4, i = idx & 15;
        ((float4*)&xs[px][0])[i] =
            *(const float4*)(z_e + (size_t)(n0 + px) * EMB_ + i * 4);
    }
    __syncthreads();

    // ---- B-fragments from LDS (2 px-tiles x 5 K-steps) ----
    h8 bfr[2][5];
    #pragma unroll
    for (int j = 0; j < 2; j++) {
        const int px = j * 32 + (lane & 31);
        #pragma unroll
        for (int s5 = 0; s5 < 4; s5++) {
            float4 u0 = *(const float4*)(&xs[px][s5 * 16 + hlf * 8]);
            float4 u1 = *(const float4*)(&xs[px][s5 * 16 + hlf * 8 + 4]);
            h8 hh;
            hh[0]=(_Float16)u0.x; hh[1]=(_Float16)u0.y; hh[2]=(_Float16)u0.z; hh[3]=(_Float16)u0.w;
            hh[4]=(_Float16)u1.x; hh[5]=(_Float16)u1.y; hh[6]=(_Float16)u1.z; hh[7]=(_Float16)u1.w;
            bfr[j][s5] = hh;
        }
        h8 hh;
        #pragma unroll
        for (int q = 0; q < 8; q++) hh[q] = (_Float16)0.f;
        if (hlf == 0) { hh[0] = (_Float16)-0.5f; hh[1] = (_Float16)-0.5f; }
        bfr[j][4] = hh;
    }

    // ---- coarse MFMA scan: wave wv covers chunks 2wv, 2wv+1 (64 tiles) ----
    const f16f kzero = {0,0,0,0,0,0,0,0,0,0,0,0,0,0,0,0};
    float s1[2], s2[2], s3[2];
    int   i1[2], i2[2];
    #pragma unroll
    for (int j = 0; j < 2; j++) { s1[j]=s2[j]=s3[j]=-3.0e38f; i1[j]=i2[j]=0; }

    const int tb = wv * 64;
    const float4* Wb = W4 + (size_t)tb * 320 + lane;
    float4 A0[5], A1[5];
    #pragma unroll
    for (int s = 0; s < 5; s++) A0[s] = Wb[s * 64];
    #pragma unroll
    for (int s = 0; s < 5; s++) A1[s] = Wb[320 + s * 64];

#define TILE_BODY(AB, TT, PF)                                                  \
    {                                                                          \
        const int gt = tb + (TT);                                              \
        f16f acc[2];                                                           \
        _Pragma("unroll")                                                      \
        for (int j = 0; j < 2; j++)                                            \
            acc[j] = __builtin_amdgcn_mfma_f32_32x32x16_f16(                   \
                __builtin_bit_cast(h8, AB[0]), bfr[j][0], kzero, 0, 0, 0);     \
        _Pragma("unroll")                                                      \
        for (int s = 1; s < 5; s++) {                                          \
            h8 a = __builtin_bit_cast(h8, AB[s]);                              \
            _Pragma("unroll")                                                  \
            for (int j = 0; j < 2; j++)                                        \
                acc[j] = __builtin_amdgcn_mfma_f32_32x32x16_f16(a, bfr[j][s],  \
                                                                acc[j],0,0,0); \
        }                                                                      \
        {                                                                      \
            const int tp = (PF) < 64 ? (PF) : 63;                              \
            const float4* wp = Wb + (size_t)tp * 320;                          \
            _Pragma("unroll")                                                  \
            for (int s = 0; s < 5; s++) AB[s] = wp[s * 64];                    \
        }                                                                      \
        _Pragma("unroll")                                                      \
        for (int j = 0; j < 2; j++) {                                          \
            float t0 = fmaxf(fmaxf(acc[j][0],  acc[j][1]),  acc[j][2]);        \
            float t1 = fmaxf(fmaxf(acc[j][3],  acc[j][4]),  acc[j][5]);        \
            float t2 = fmaxf(fmaxf(acc[j][6],  acc[j][7]),  acc[j][8]);        \
            float t3 = fmaxf(fmaxf(acc[j][9],  acc[j][10]), acc[j][11]);       \
            float t4 = fmaxf(fmaxf(acc[j][12], acc[j][13]), acc[j][14]);       \
            float v  = fmaxf(fmaxf(fmaxf(t0, t1), fmaxf(t2, t3)),              \
                             fmaxf(t4, acc[j][15]));                           \
            v = fmaxf(v, __shfl_xor(v, 32));                                   \
            bool c1 = v > s1[j];                                               \
            bool c2 = v > s2[j];                                               \
            int  cand = c1 ? i1[j] : gt;                                       \
            i2[j] = c2 ? cand : i2[j];                                         \
            s3[j] = fmaxf(fminf(s2[j], v), s3[j]);                             \
            s3[j] = fminf(s3[j], fmaxf(s2[j], v));                             \
            s2[j] = fmaxf(fminf(s1[j], v), fminf(s2[j], fmaxf(s1[j], v)));     \
            i1[j] = c1 ? gt : i1[j];                                           \
            s1[j] = fmaxf(s1[j], v);                                           \
        }                                                                      \
        if (((TT) & 31) == 31) {                                               \
            const int ch = (tb + (TT)) >> 5;                                   \
            if (lane < 32) {                                                   \
                _Pragma("unroll")                                              \
                for (int j = 0; j < 2; j++) {                                  \
                    const int cell = (j * 32 + lane) * 8 + ch;                 \
                    s1s[cell] = s1[j]; s2s[cell] = s2[j]; s3s[cell] = s3[j];   \
                    i1s[cell] = (short)i1[j]; i2s[cell] = (short)i2[j];        \
                }                                                              \
            }                                                                  \
            _Pragma("unroll")                                                  \
            for (int j = 0; j < 2; j++) {                                      \
                s1[j]=s2[j]=s3[j]=-3.0e38f; i1[j]=i2[j]=0;                     \
            }                                                                  \
        }                                                                      \
    }

    for (int tt = 0; tt < 64; tt += 2) {
        TILE_BODY(A0, tt,     tt + 2)
        TILE_BODY(A1, tt + 1, tt + 3)
    }
#undef TILE_BODY
    __syncthreads();

    // ---- certify ----
    if (tid < 64) {
        float s1g = s1s[tid * 8];
        #pragma unroll
        for (int c = 1; c < 8; c++) s1g = fmaxf(s1g, s1s[tid * 8 + c]);
        float E = 0.00125f * sqrtf(xsq[n0 + tid] * wm_s) + 1e-5f * wm_s + 3e-4f;
        thr_s[tid] = s1g - 2.0f * E;
    }
    __syncthreads();
    // ---- push candidate (px, tile) pairs; tiles are GLOBAL ids (0..255) ----
    #pragma unroll
    for (int k = 0; k < 2; k++) {
        const int cell = k * 256 + tid;
        const int px = cell >> 3, ch = cell & 7;
        const float th = thr_s[px];
        const float cs1 = s1s[cell], cs2 = s2s[cell], cs3 = s3s[cell];
        if (cs3 >= th) {
            int pos = atomicAdd(&npair_s, 32);
            if (pos + 32 <= CAPP) {
                for (int t = 0; t < 32; t++)
                    pairs[pos + t] = (px << 8) | (ch * 32 + t);
            } else {
                for (int t = 0; t < 32; t++)
                    if (pos + t < CAPP) pairs[pos + t] = -1;
                smask[px] = 1;
            }
        } else {
            if (cs1 >= th) {
                int pos = atomicAdd(&npair_s, 1);
                if (pos < CAPP) pairs[pos] = (px << 8) | (int)i1s[cell];
                else smask[px] = 1;
            }
            if (cs2 >= th) {
                int pos = atomicAdd(&npair_s, 1);
                if (pos < CAPP) pairs[pos] = (px << 8) | (int)i2s[cell];
                else smask[px] = 1;
            }
        }
    }
    __syncthreads();
    const int np = npair_s < CAPP ? npair_s : CAPP;

    // ---- COALESCED drain: one tile per wave-iter; 8 x 1KB contiguous loads.
    // lane covers code q*4+(lane>>4), dims (lane&15)*4. Butterfly over 16 lanes.
    const int lg = lane >> 4;
    const int ld = lane & 15;
    for (int i = wv; i < np; i += 4) {
        const int pr = pairs[i];
        if (pr < 0) continue;
        const int p = pr >> 8;
        if (smask[p]) continue;
        const int t = pr & 255;
        const float4* tb4 = (const float4*)(ew + (size_t)t * 2048);
        float4 wq[8];
        #pragma unroll
        for (int q = 0; q < 8; q++) wq[q] = tb4[q * 64 + lane];
        const float4 xq = *(const float4*)(&xs[p][ld * 4]);
        unsigned long long best = ~0ULL;
        #pragma unroll
        for (int q = 0; q < 8; q++) {
            float dp = wq[q].x*xq.x + wq[q].y*xq.y + wq[q].z*xq.z + wq[q].w*xq.w;
            dp += __shfl_xor(dp, 1);
            dp += __shfl_xor(dp, 2);
            dp += __shfl_xor(dp, 4);
            dp += __shfl_xor(dp, 8);
            const int m = t * 32 + q * 4 + lg;
            unsigned long long key = pack_key(fmaf(-2.f, dp, wsq[m]), m);
            best = key < best ? key : best;
        }
        { unsigned long long o = __shfl_xor(best, 16); best = o < best ? o : best; }
        { unsigned long long o = __shfl_xor(best, 32); best = o < best ? o : best; }
        if (lane == 0) {
            unsigned long long cur = wbest[wv][p];
            wbest[wv][p] = best < cur ? best : cur;
        }
    }
    // ---- overflow fallback: full 256-tile coalesced rescan (rare) ----
    for (int p = wv; p < 64; p += 4) {
        if (!smask[p]) continue;
        const float4 xq = *(const float4*)(&xs[p][ld * 4]);
        unsigned long long bk = ~0ULL;
        for (int t = 0; t < 256; t++) {
            const float4* tb4 = (const float4*)(ew + (size_t)t * 2048);
            #pragma unroll
            for (int q = 0; q < 8; q++) {
                float4 wv4 = tb4[q * 64 + lane];
                float dp = wv4.x*xq.x + wv4.y*xq.y + wv4.z*xq.z + wv4.w*xq.w;
                dp += __shfl_xor(dp, 1);
                dp += __shfl_xor(dp, 2);
                dp += __shfl_xor(dp, 4);
                dp += __shfl_xor(dp, 8);
                const int m = t * 32 + q * 4 + lg;
                unsigned long long key = pack_key(fmaf(-2.f, dp, wsq[m]), m);
                bk = key < bk ? key : bk;
            }
        }
        { unsigned long long o = __shfl_xor(bk, 16); bk = o < bk ? o : bk; }
        { unsigned long long o = __shfl_xor(bk, 32); bk = o < bk ? o : bk; }
        if (lane == 0) {
            unsigned long long cur = wbest[wv][p];
            wbest[wv][p] = bk < cur ? bk : cur;
        }
    }
    __syncthreads();
    if (tid < 64) {
        unsigned long long k0 = wbest[0][tid];
        unsigned long long k1 = wbest[1][tid];
        unsigned long long k2 = wbest[2][tid];
        unsigned long long k3 = wbest[3][tid];
        k0 = k1 < k0 ? k1 : k0;
        k2 = k3 < k2 ? k3 : k2;
        k0 = k2 < k0 ? k2 : k0;
        const int win = (int)(unsigned)(k0 & 0xFFFFFFFFULL);
        winner_s[tid] = win;
        out[IND_OFF + n0 + tid] = (float)win;
    }
    __syncthreads();
    // ---- gather winner rows (4 thr/px), z_q writes, loss partials ----
    float lsum = 0.f;
    {
        const int px = tid >> 2, sg = tid & 3;
        const int win = winner_s[px];
        const float4* wr = (const float4*)(ew + (size_t)win * EMB_ + sg * 16);
        float4* xr  = (float4*)(&xs[px][sg * 16]);
        float4* zq4 = (float4*)(out + ZQ_OFF + (size_t)(n0 + px) * EMB_ + sg * 16);
        #pragma unroll
        for (int i = 0; i < 4; i++) {
            float4 w4v = wr[i];
            float4 z4  = xr[i];
            float d0 = w4v.x - z4.x, d1 = w4v.y - z4.y;
            float d2 = w4v.z - z4.z, d3 = w4v.w - z4.w;
            lsum += d0*d0 + d1*d1 + d2*d2 + d3*d3;
            xr[i]  = w4v;
            zq4[i] = w4v;
        }
    }
    __syncthreads();
    // ---- transposed out writes (64e x 64px, 256-B runs) ----
    {
        const int bI  = n0 >> 10;
        const int hw0 = n0 & 1023;
        float* ob = out + OUT_OFF + (size_t)bI * (EMB_ * 1024) + hw0;
        #pragma unroll
        for (int r = 0; r < 16; r++) {
            const int idx = r * 256 + tid;
            const int e = idx >> 6, px = idx & 63;
            ob[(size_t)e * 1024 + px] = xs[px][e];
        }
    }
    // ---- loss reduction + final scalar ----
    lred[tid] = lsum;
    __syncthreads();
    for (int o = 128; o > 0; o >>= 1) {
        if (tid < o) lred[tid] += lred[tid + o];
        __syncthreads();
    }
    if (tid == 0) {
        atomicAdd(lacc, lred[0]);
        __threadfence();
        int old = atomicAdd(done, 1);
        if (old == (int)gridDim.x - 1) {
            float tot = atomicAdd(lacc, 0.0f);
            out[LOSS_OFF] = 12.5f * (tot / 2097152.0f);
        }
    }
}

// ---------------------------------------------------------------------------
extern "C" void kernel_launch(void* const* d_in, const int* in_sizes, int n_in,
                              void* d_out, int out_size, void* d_ws, size_t ws_size,
                              hipStream_t stream)
{
    const float* z  = (const float*)d_in[0];
    const float* pw = (const float*)d_in[1];
    const float* pb = (const float*)d_in[2];
    const float* ew = (const float*)d_in[3];
    float* out = (float*)d_out;

    char* ws = (char*)d_ws;
    float4* W4   = (float4*)(ws);                      // 1,310,720
    float*  xsq  = (float*) (ws + 1310720);            //   131,072
    float*  wsq  = (float*) (ws + 1441792);            //    32,768
    float*  wsqp = (float*) (ws + 1474560);            //       128
    float*  lacc = (float*) (ws + 1474688);            //         4
    int*    done = (int*)   (ws + 1474692);            //         4

    float* z_e = out + ZQ_OFF;   // z_q_flat region doubles as z_e scratch

    hipLaunchKernelGGL(k_wpack,  dim3(32),  dim3(256), 0, stream,
                       ew, W4, wsq, wsqp, lacc, done);
    hipLaunchKernelGGL(k_proj,   dim3(512), dim3(256), 0, stream,
                       z, pw, pb, z_e, xsq);
    hipLaunchKernelGGL(k_fused2, dim3(512), dim3(256), 0, stream,
                       W4, z_e, xsq, wsqp, wsq, ew, out, lacc, done);
}

// Round 10
// 173.961 us; speedup vs baseline: 1.2582x; 1.0729x over previous
//
#include <hip/hip_runtime.h>

// Problem constants
#define NPIX   32768      // B*H*W
#define NEMB_  8192
#define EMB_   64
#define CH_    128
#define CAPP   768        // LDS pair-queue capacity

// d_out layout (float elements)
#define OUT_OFF  0
#define ZQ_OFF   2097152
#define LOSS_OFF 4194304
#define IND_OFF  4194305

typedef _Float16 h8   __attribute__((ext_vector_type(8)));
typedef float    f16f __attribute__((ext_vector_type(16)));

// ---------------------------------------------------------------------------
// K1: codebook W-fragment pack + wsq + per-block max + pw transpose + init.
// grid 32.  pwT[c*64+e] = pw[e*CH+c] (for k_proj's scalar loads).
__global__ __launch_bounds__(256) void k_wpack(
    const float* __restrict__ ew, const float* __restrict__ pw,
    float4* __restrict__ W4, float* __restrict__ pwT,
    float* __restrict__ wsq, float* __restrict__ wsqp,
    float* __restrict__ lacc, int* __restrict__ done)
{
    const int tid = threadIdx.x;
    // pw transpose: 8192 elements over 32 blocks
    {
        const int i = blockIdx.x * 256 + tid;
        const float v = pw[i];
        const int e = i >> 7, c = i & 127;
        pwT[c * 64 + e] = v;
    }
    const int m = blockIdx.x * 256 + tid;
    const float4* wr = (const float4*)(ew + (size_t)m * EMB_);
    float w[EMB_];
    float s = 0.f;
    #pragma unroll
    for (int i = 0; i < 16; i++) {
        float4 v = wr[i];
        w[4*i] = v.x; w[4*i+1] = v.y; w[4*i+2] = v.z; w[4*i+3] = v.w;
        s += v.x*v.x + v.y*v.y + v.z*v.z + v.w*v.w;
    }
    wsq[m] = s;
    float sh = (float)(_Float16)s;
    float sl = s - sh;
    const int t  = m >> 5;
    const int li = m & 31;
    #pragma unroll
    for (int s5 = 0; s5 < 4; s5++) {
        #pragma unroll
        for (int h = 0; h < 2; h++) {
            h8 hh;
            #pragma unroll
            for (int j = 0; j < 8; j++) hh[j] = (_Float16)w[s5 * 16 + h * 8 + j];
            W4[(size_t)(t * 5 + s5) * 64 + h * 32 + li] = __builtin_bit_cast(float4, hh);
        }
    }
    {
        h8 hh;
        #pragma unroll
        for (int j = 0; j < 8; j++) hh[j] = (_Float16)0.f;
        hh[0] = (_Float16)sh; hh[1] = (_Float16)sl;
        W4[(size_t)(t * 5 + 4) * 64 + 0 * 32 + li] = __builtin_bit_cast(float4, hh);
        #pragma unroll
        for (int j = 0; j < 8; j++) hh[j] = (_Float16)0.f;
        W4[(size_t)(t * 5 + 4) * 64 + 1 * 32 + li] = __builtin_bit_cast(float4, hh);
    }
    __shared__ float red[256];
    red[tid] = s;
    __syncthreads();
    for (int o = 128; o > 0; o >>= 1) {
        if (tid < o) red[tid] = fmaxf(red[tid], red[tid + o]);
        __syncthreads();
    }
    if (tid == 0) wsqp[blockIdx.x] = red[0];
    if (blockIdx.x == 0 && tid == 0) { *lacc = 0.f; *done = 0; }
}

// ---------------------------------------------------------------------------
// K2: projection via scalar-pipe weight loads. grid 512, block 256 =
// 64 px x 4 e-quarters. eq forced to SGPR -> pwT reads become s_load.
__global__ __launch_bounds__(256) void k_proj(
    const float* __restrict__ z, const float* __restrict__ pwT,
    const float* __restrict__ pb, float* __restrict__ z_e,
    float* __restrict__ xsq)
{
    __shared__ float xp[4][64];
    const int tid  = threadIdx.x;
    const int px   = tid & 63;
    const int eqv  = tid >> 6;                               // wave-uniform
    const int eq16 = __builtin_amdgcn_readfirstlane(eqv << 4); // SGPR
    const int n  = blockIdx.x * 64 + px;
    const int b  = n >> 10;
    const int hw = n & 1023;
    const float* zp = z + (size_t)b * (CH_ * 1024) + hw;

    float acc[16];
    #pragma unroll
    for (int j = 0; j < 16; j++) acc[j] = 0.f;

    #pragma unroll 4
    for (int c = 0; c < CH_; c++) {
        const float zv = zp[(size_t)c * 1024];               // coalesced
        const float4* wr = (const float4*)(pwT + c * 64 + eq16);  // uniform -> s_load
        float4 w0 = wr[0], w1 = wr[1], w2 = wr[2], w3 = wr[3];
        acc[0]  = fmaf(zv, w0.x, acc[0]);  acc[1]  = fmaf(zv, w0.y, acc[1]);
        acc[2]  = fmaf(zv, w0.z, acc[2]);  acc[3]  = fmaf(zv, w0.w, acc[3]);
        acc[4]  = fmaf(zv, w1.x, acc[4]);  acc[5]  = fmaf(zv, w1.y, acc[5]);
        acc[6]  = fmaf(zv, w1.z, acc[6]);  acc[7]  = fmaf(zv, w1.w, acc[7]);
        acc[8]  = fmaf(zv, w2.x, acc[8]);  acc[9]  = fmaf(zv, w2.y, acc[9]);
        acc[10] = fmaf(zv, w2.z, acc[10]); acc[11] = fmaf(zv, w2.w, acc[11]);
        acc[12] = fmaf(zv, w3.x, acc[12]); acc[13] = fmaf(zv, w3.y, acc[13]);
        acc[14] = fmaf(zv, w3.z, acc[14]); acc[15] = fmaf(zv, w3.w, acc[15]);
    }

    const float4* pb4 = (const float4*)(pb + eq16);
    float4 b0 = pb4[0], b1 = pb4[1], b2 = pb4[2], b3 = pb4[3];
    float bb[16] = {b0.x,b0.y,b0.z,b0.w, b1.x,b1.y,b1.z,b1.w,
                    b2.x,b2.y,b2.z,b2.w, b3.x,b3.y,b3.z,b3.w};
    float sq = 0.f;
    #pragma unroll
    for (int j = 0; j < 16; j++) { acc[j] += bb[j]; sq += acc[j] * acc[j]; }

    float4* zo = (float4*)(z_e + (size_t)n * EMB_ + eq16);
    zo[0] = make_float4(acc[0],  acc[1],  acc[2],  acc[3]);
    zo[1] = make_float4(acc[4],  acc[5],  acc[6],  acc[7]);
    zo[2] = make_float4(acc[8],  acc[9],  acc[10], acc[11]);
    zo[3] = make_float4(acc[12], acc[13], acc[14], acc[15]);
    xp[eqv][px] = sq;
    __syncthreads();
    if (tid < 64)
        xsq[blockIdx.x * 64 + tid] = xp[0][tid] + xp[1][tid] + xp[2][tid] + xp[3][tid];
}

// ---------------------------------------------------------------------------
// ordered-float key: lexicographic (dist, index) min == np argmin semantics
__device__ __forceinline__ unsigned long long pack_key(float d, int m)
{
    unsigned fb = __float_as_uint(d);
    fb ^= ((int)fb < 0) ? 0xFFFFFFFFu : 0x80000000u;
    return ((unsigned long long)fb << 32) | (unsigned)m;
}

// ---------------------------------------------------------------------------
// K3 fused: 128 px/block, 512 threads (8 waves), wave = 1 chunk x 4 B-tiles.
// grid 256 (1 block/CU, 2 waves/SIMD). LDS stats -> certify -> coalesced
// drain (LDS atomicMin) -> finalize + loss.
__global__ __launch_bounds__(512, 2) void k_fused3(
    const float4* __restrict__ W4, const float* __restrict__ z_e,
    const float* __restrict__ xsq, const float* __restrict__ wsqp,
    const float* __restrict__ wsq, const float* __restrict__ ew,
    float* __restrict__ out, float* __restrict__ lacc, int* __restrict__ done)
{
    __shared__ __align__(16) float xs[128][68];      // z_e rows, later winners
    __shared__ float s1s[1024], s2s[1024], s3s[1024];  // [px][ch]
    __shared__ short i1s[1024], i2s[1024];
    __shared__ float thr_s[128];
    __shared__ int   pairs[CAPP];
    __shared__ unsigned long long pbest[128];
    __shared__ int   winner_s[128];
    __shared__ int   smask[128];
    __shared__ float wred[8];
    __shared__ int   npair_s;
    __shared__ float wm_s;

    const int tid  = threadIdx.x;
    const int wv   = tid >> 6;                       // 0..7 = chunk
    const int lane = tid & 63;
    const int n0   = blockIdx.x * 128;
    const int hlf  = lane >> 5;

    if (tid == 0) npair_s = 0;
    if (tid < 128) { smask[tid] = 0; pbest[tid] = ~0ULL; }
    if (tid < 32) {
        float w = wsqp[tid];
        #pragma unroll
        for (int o = 16; o > 0; o >>= 1) w = fmaxf(w, __shfl_xor(w, o));
        if (tid == 0) wm_s = w;
    }
    // ---- stage xs coalesced (128 px x 64 f) ----
    #pragma unroll
    for (int k = 0; k < 4; k++) {
        const int idx = k * 512 + tid;
        const int px = idx >> 4, i = idx & 15;
        ((float4*)&xs[px][0])[i] =
            *(const float4*)(z_e + (size_t)(n0 + px) * EMB_ + i * 4);
    }
    __syncthreads();

    // ---- B-fragments from LDS (4 px-tiles x 5 K-steps) ----
    h8 bfr[4][5];
    #pragma unroll
    for (int j = 0; j < 4; j++) {
        const int px = j * 32 + (lane & 31);
        #pragma unroll
        for (int s5 = 0; s5 < 4; s5++) {
            float4 u0 = *(const float4*)(&xs[px][s5 * 16 + hlf * 8]);
            float4 u1 = *(const float4*)(&xs[px][s5 * 16 + hlf * 8 + 4]);
            h8 hh;
            hh[0]=(_Float16)u0.x; hh[1]=(_Float16)u0.y; hh[2]=(_Float16)u0.z; hh[3]=(_Float16)u0.w;
            hh[4]=(_Float16)u1.x; hh[5]=(_Float16)u1.y; hh[6]=(_Float16)u1.z; hh[7]=(_Float16)u1.w;
            bfr[j][s5] = hh;
        }
        h8 hh;
        #pragma unroll
        for (int q = 0; q < 8; q++) hh[q] = (_Float16)0.f;
        if (hlf == 0) { hh[0] = (_Float16)-0.5f; hh[1] = (_Float16)-0.5f; }
        bfr[j][4] = hh;
    }

    // ---- coarse MFMA scan: wave wv covers chunk wv (32 tiles) ----
    const f16f kzero = {0,0,0,0,0,0,0,0,0,0,0,0,0,0,0,0};
    float s1[4], s2[4], s3[4];
    int   i1[4], i2[4];
    #pragma unroll
    for (int j = 0; j < 4; j++) { s1[j]=s2[j]=s3[j]=-3.0e38f; i1[j]=i2[j]=0; }

    const int tb = wv * 32;
    const float4* Wb = W4 + (size_t)tb * 320 + lane;
    float4 A0[5], A1[5];
    #pragma unroll
    for (int s = 0; s < 5; s++) A0[s] = Wb[s * 64];
    #pragma unroll
    for (int s = 0; s < 5; s++) A1[s] = Wb[320 + s * 64];

#define TILE_BODY(AB, TT, PF)                                                  \
    {                                                                          \
        const int gt = tb + (TT);                                              \
        f16f acc[4];                                                           \
        _Pragma("unroll")                                                      \
        for (int j = 0; j < 4; j++)                                            \
            acc[j] = __builtin_amdgcn_mfma_f32_32x32x16_f16(                   \
                __builtin_bit_cast(h8, AB[0]), bfr[j][0], kzero, 0, 0, 0);     \
        _Pragma("unroll")                                                      \
        for (int s = 1; s < 5; s++) {                                          \
            h8 a = __builtin_bit_cast(h8, AB[s]);                              \
            _Pragma("unroll")                                                  \
            for (int j = 0; j < 4; j++)                                        \
                acc[j] = __builtin_amdgcn_mfma_f32_32x32x16_f16(a, bfr[j][s],  \
                                                                acc[j],0,0,0); \
        }                                                                      \
        {                                                                      \
            const int tp = (PF) < 32 ? (PF) : 31;                              \
            const float4* wp = Wb + (size_t)tp * 320;                          \
            _Pragma("unroll")                                                  \
            for (int s = 0; s < 5; s++) AB[s] = wp[s * 64];                    \
        }                                                                      \
        _Pragma("unroll")                                                      \
        for (int j = 0; j < 4; j++) {                                          \
            float t0 = fmaxf(fmaxf(acc[j][0],  acc[j][1]),  acc[j][2]);        \
            float t1 = fmaxf(fmaxf(acc[j][3],  acc[j][4]),  acc[j][5]);        \
            float t2 = fmaxf(fmaxf(acc[j][6],  acc[j][7]),  acc[j][8]);        \
            float t3 = fmaxf(fmaxf(acc[j][9],  acc[j][10]), acc[j][11]);       \
            float t4 = fmaxf(fmaxf(acc[j][12], acc[j][13]), acc[j][14]);       \
            float v  = fmaxf(fmaxf(fmaxf(t0, t1), fmaxf(t2, t3)),              \
                             fmaxf(t4, acc[j][15]));                           \
            v = fmaxf(v, __shfl_xor(v, 32));                                   \
            bool c1 = v > s1[j];                                               \
            bool c2 = v > s2[j];                                               \
            int  cand = c1 ? i1[j] : gt;                                       \
            i2[j] = c2 ? cand : i2[j];                                         \
            s3[j] = fmaxf(fminf(s2[j], v), s3[j]);                             \
            s3[j] = fminf(s3[j], fmaxf(s2[j], v));                             \
            s2[j] = fmaxf(fminf(s1[j], v), fminf(s2[j], fmaxf(s1[j], v)));     \
            i1[j] = c1 ? gt : i1[j];                                           \
            s1[j] = fmaxf(s1[j], v);                                           \
        }                                                                      \
    }

    for (int tt = 0; tt < 32; tt += 2) {
        TILE_BODY(A0, tt,     tt + 2)
        TILE_BODY(A1, tt + 1, tt + 3)
    }
#undef TILE_BODY

    if (lane < 32) {
        #pragma unroll
        for (int j = 0; j < 4; j++) {
            const int cell = (j * 32 + lane) * 8 + wv;
            s1s[cell] = s1[j]; s2s[cell] = s2[j]; s3s[cell] = s3[j];
            i1s[cell] = (short)i1[j]; i2s[cell] = (short)i2[j];
        }
    }
    __syncthreads();

    // ---- certify ----
    if (tid < 128) {
        float s1g = s1s[tid * 8];
        #pragma unroll
        for (int c = 1; c < 8; c++) s1g = fmaxf(s1g, s1s[tid * 8 + c]);
        float E = 0.00125f * sqrtf(xsq[n0 + tid] * wm_s) + 1e-5f * wm_s + 3e-4f;
        thr_s[tid] = s1g - 2.0f * E;
    }
    __syncthreads();
    // ---- push candidate (px, tile) pairs (global tile ids 0..255) ----
    #pragma unroll
    for (int k = 0; k < 2; k++) {
        const int cell = k * 512 + tid;
        const int px = cell >> 3, ch = cell & 7;
        const float th = thr_s[px];
        const float cs1 = s1s[cell], cs2 = s2s[cell], cs3 = s3s[cell];
        if (cs3 >= th) {
            int pos = atomicAdd(&npair_s, 32);
            if (pos + 32 <= CAPP) {
                for (int t = 0; t < 32; t++)
                    pairs[pos + t] = (px << 8) | (ch * 32 + t);
            } else {
                for (int t = 0; t < 32; t++)
                    if (pos + t < CAPP) pairs[pos + t] = -1;
                smask[px] = 1;
            }
        } else {
            if (cs1 >= th) {
                int pos = atomicAdd(&npair_s, 1);
                if (pos < CAPP) pairs[pos] = (px << 8) | (int)i1s[cell];
                else smask[px] = 1;
            }
            if (cs2 >= th) {
                int pos = atomicAdd(&npair_s, 1);
                if (pos < CAPP) pairs[pos] = (px << 8) | (int)i2s[cell];
                else smask[px] = 1;
            }
        }
    }
    __syncthreads();
    const int np = npair_s < CAPP ? npair_s : CAPP;

    // ---- coalesced drain: one tile per wave-iter; 8 x 1KB contiguous ----
    const int lg = lane >> 4;
    const int ld = lane & 15;
    for (int i = wv; i < np; i += 8) {
        const int pr = pairs[i];
        if (pr < 0) continue;
        const int p = pr >> 8;
        if (smask[p]) continue;
        const int t = pr & 255;
        const float4* tb4 = (const float4*)(ew + (size_t)t * 2048);
        float4 wq[8];
        #pragma unroll
        for (int q = 0; q < 8; q++) wq[q] = tb4[q * 64 + lane];
        const float4 xq = *(const float4*)(&xs[p][ld * 4]);
        unsigned long long best = ~0ULL;
        #pragma unroll
        for (int q = 0; q < 8; q++) {
            float dp = wq[q].x*xq.x + wq[q].y*xq.y + wq[q].z*xq.z + wq[q].w*xq.w;
            dp += __shfl_xor(dp, 1);
            dp += __shfl_xor(dp, 2);
            dp += __shfl_xor(dp, 4);
            dp += __shfl_xor(dp, 8);
            const int m = t * 32 + q * 4 + lg;
            unsigned long long key = pack_key(fmaf(-2.f, dp, wsq[m]), m);
            best = key < best ? key : best;
        }
        { unsigned long long o = __shfl_xor(best, 16); best = o < best ? o : best; }
        { unsigned long long o = __shfl_xor(best, 32); best = o < best ? o : best; }
        if (lane == 0) atomicMin(&pbest[p], best);
    }
    // ---- overflow fallback: full codebook rescan (statistically never) ----
    for (int p = wv; p < 128; p += 8) {
        if (!smask[p]) continue;
        const float4 xq = *(const float4*)(&xs[p][ld * 4]);
        unsigned long long bk = ~0ULL;
        for (int t = 0; t < 256; t++) {
            const float4* tb4 = (const float4*)(ew + (size_t)t * 2048);
            #pragma unroll
            for (int q = 0; q < 8; q++) {
                float4 wv4 = tb4[q * 64 + lane];
                float dp = wv4.x*xq.x + wv4.y*xq.y + wv4.z*xq.z + wv4.w*xq.w;
                dp += __shfl_xor(dp, 1);
                dp += __shfl_xor(dp, 2);
                dp += __shfl_xor(dp, 4);
                dp += __shfl_xor(dp, 8);
                const int m = t * 32 + q * 4 + lg;
                unsigned long long key = pack_key(fmaf(-2.f, dp, wsq[m]), m);
                bk = key < bk ? key : bk;
            }
        }
        { unsigned long long o = __shfl_xor(bk, 16); bk = o < bk ? o : bk; }
        { unsigned long long o = __shfl_xor(bk, 32); bk = o < bk ? o : bk; }
        if (lane == 0) atomicMin(&pbest[p], bk);
    }
    __syncthreads();
    if (tid < 128) {
        const int win = (int)(unsigned)(pbest[tid] & 0xFFFFFFFFULL);
        winner_s[tid] = win;
        out[IND_OFF + n0 + tid] = (float)win;
    }
    __syncthreads();
    // ---- gather winner rows (4 thr/px), z_q writes, loss partials ----
    float lsum = 0.f;
    {
        const int px = tid >> 2, sg = tid & 3;
        const int win = winner_s[px];
        const float4* wr = (const float4*)(ew + (size_t)win * EMB_ + sg * 16);
        float4* xr  = (float4*)(&xs[px][sg * 16]);
        float4* zq4 = (float4*)(out + ZQ_OFF + (size_t)(n0 + px) * EMB_ + sg * 16);
        #pragma unroll
        for (int i = 0; i < 4; i++) {
            float4 w4v = wr[i];
            float4 z4  = xr[i];
            float d0 = w4v.x - z4.x, d1 = w4v.y - z4.y;
            float d2 = w4v.z - z4.z, d3 = w4v.w - z4.w;
            lsum += d0*d0 + d1*d1 + d2*d2 + d3*d3;
            xr[i]  = w4v;
            zq4[i] = w4v;
        }
    }
    __syncthreads();
    // ---- transposed out writes (64e x 128px, 512-B runs) ----
    {
        const int bI  = n0 >> 10;
        const int hw0 = n0 & 1023;
        float* ob = out + OUT_OFF + (size_t)bI * (EMB_ * 1024) + hw0;
        #pragma unroll
        for (int r = 0; r < 16; r++) {
            const int idx = r * 512 + tid;
            const int e = idx >> 7, px = idx & 127;
            ob[(size_t)e * 1024 + px] = xs[px][e];
        }
    }
    // ---- loss reduction + final scalar ----
    {
        float v = lsum;
        #pragma unroll
        for (int o = 1; o < 64; o <<= 1) v += __shfl_xor(v, o);
        if (lane == 0) wred[wv] = v;
    }
    __syncthreads();
    if (tid == 0) {
        float s = wred[0];
        #pragma unroll
        for (int k = 1; k < 8; k++) s += wred[k];
        atomicAdd(lacc, s);
        __threadfence();
        int old = atomicAdd(done, 1);
        if (old == (int)gridDim.x - 1) {
            float tot = atomicAdd(lacc, 0.0f);
            out[LOSS_OFF] = 12.5f * (tot / 2097152.0f);
        }
    }
}

// ---------------------------------------------------------------------------
extern "C" void kernel_launch(void* const* d_in, const int* in_sizes, int n_in,
                              void* d_out, int out_size, void* d_ws, size_t ws_size,
                              hipStream_t stream)
{
    const float* z  = (const float*)d_in[0];
    const float* pw = (const float*)d_in[1];
    const float* pb = (const float*)d_in[2];
    const float* ew = (const float*)d_in[3];
    float* out = (float*)d_out;

    char* ws = (char*)d_ws;
    float4* W4   = (float4*)(ws);                      // 1,310,720
    float*  pwT  = (float*) (ws + 1310720);            //    32,768
    float*  xsq  = (float*) (ws + 1343488);            //   131,072
    float*  wsq  = (float*) (ws + 1474560);            //    32,768
    float*  wsqp = (float*) (ws + 1507328);            //       128
    float*  lacc = (float*) (ws + 1507456);            //         4
    int*    done = (int*)   (ws + 1507460);            //         4

    float* z_e = out + ZQ_OFF;   // z_q_flat region doubles as z_e scratch

    hipLaunchKernelGGL(k_wpack,  dim3(32),  dim3(256), 0, stream,
                       ew, pw, W4, pwT, wsq, wsqp, lacc, done);
    hipLaunchKernelGGL(k_proj,   dim3(512), dim3(256), 0, stream,
                       z, pwT, pb, z_e, xsq);
    hipLaunchKernelGGL(k_fused3, dim3(256), dim3(512), 0, stream,
                       W4, z_e, xsq, wsqp, wsq, ew, out, lacc, done);
}